// Round 10
// baseline (71.259 us; speedup 1.0000x reference)
//
#include <hip/hip_runtime.h>

// R10: producer/consumer wave specialization.
//   256 blocks (1/CU), 512 thr: waves 0-3 compute, 4-7 copy.
//   Block owns 128 rows = 4 tiles of 32. Copy waves stream tile t+1's x
//   FLAT+COALESCED (fix for the fragmented-fetch disease: prior rounds read
//   each row in 128-256B slivers -> ~800GB/s effective DRAM), convert to
//   bf16, ds_write into double-buffered [32][840] LDS tile (832 = 784+zeros
//   -> no K-tail; +8 pad -> 2-way banks). Compute waves: GEMM1 over the
//   resident tile (A = 1 ds_read_b128/frag, no cvt in hot loop; B from
//   L2-resident weff, distance-1 full-window reg prefetch), then GEMM2/3.
//   2 barriers per tile; copy splits across them. 1 MFMA wave + 1 copy wave
//   per SIMD = m114 free overlap.

typedef __attribute__((ext_vector_type(8))) short bf16x8;
typedef __attribute__((ext_vector_type(4))) float f32x4;

#define KP1 832     // Weff K padded (784 -> 13*64)
#define NP  112     // hidden N padded (100 -> 7*16)
#define K2P 128     // GEMM2/3 K padded
#define NT  512
#define TILES 4
#define ROWS 32
#define XC  840     // ushorts per xs row (832 data + 8 pad)

#define W2T_OFF (NP * KP1)              // 93184
#define W3T_OFF (W2T_OFF + NP * K2P)    // 107520

#define SBAR0 __builtin_amdgcn_sched_barrier(0)

__device__ __forceinline__ unsigned short f2bf(float f) {
    unsigned int u = __float_as_uint(f);
    u += 0x7FFFu + ((u >> 16) & 1u);    // RNE
    return (unsigned short)(u >> 16);
}

__device__ __forceinline__ unsigned int pkbf(float a, float b) {
    unsigned int r;
    asm("v_cvt_pk_bf16_f32 %0, %1, %2" : "=v"(r) : "v"(a), "v"(b));
    return r;
}

// ---------------- Kernel A: weights -> bf16, transposed, padded (R9's)
__global__ void build_weights(const float* __restrict__ w_conv,
                              const float* __restrict__ W1,
                              const float* __restrict__ W2,
                              const float* __restrict__ W3,
                              unsigned short* __restrict__ ws) {
    const int idx = blockIdx.x * 256 + threadIdx.x;
    const int WEFF_T = 28 * KP1;
    if (idx < WEFF_T) {
        const int j4 = idx / KP1, p = idx % KP1;
        const int j = j4 * 4;
        float a0 = 0.f, a1 = 0.f, a2 = 0.f, a3 = 0.f;
        if (p < 784 && j4 < 25) {
            const int y = p / 28, xx = p % 28;
#pragma unroll
            for (int ky = 0; ky < 3; ++ky) {
                const int py = y - ky;
                if (py < 0 || py >= 26) continue;
#pragma unroll
                for (int kx = 0; kx < 3; ++kx) {
                    const int px = xx - kx;
                    if (px < 0 || px >= 26) continue;
                    const float wc = w_conv[ky * 3 + kx];
                    const float4 w = *reinterpret_cast<const float4*>(
                        W1 + (size_t)(py * 26 + px) * 100 + j);
                    a0 = fmaf(wc, w.x, a0); a1 = fmaf(wc, w.y, a1);
                    a2 = fmaf(wc, w.z, a2); a3 = fmaf(wc, w.w, a3);
                }
            }
        }
        ws[(size_t)(j + 0) * KP1 + p] = f2bf(a0);
        ws[(size_t)(j + 1) * KP1 + p] = f2bf(a1);
        ws[(size_t)(j + 2) * KP1 + p] = f2bf(a2);
        ws[(size_t)(j + 3) * KP1 + p] = f2bf(a3);
    } else if (idx < WEFF_T + NP * K2P) {
        const int r = idx - WEFF_T;
        const int col = r / K2P, k = r % K2P;
        float v = (col < 100 && k < 100) ? W2[k * 100 + col] : 0.f;
        ws[W2T_OFF + r] = f2bf(v);
    } else if (idx < WEFF_T + NP * K2P + 16 * K2P) {
        const int r = idx - WEFF_T - NP * K2P;
        const int col = r / K2P, k = r % K2P;
        float v = (col < 10 && k < 100) ? W3[k * 10 + col] : 0.f;
        ws[W3T_OFF + r] = f2bf(v);
    }
}

// ---------------- Kernel B: fused, producer/consumer
__global__ __launch_bounds__(NT, 2)
void fused(const float* __restrict__ x,
           const unsigned short* __restrict__ wst,
           const float* __restrict__ b1,
           const float* __restrict__ b2,
           const float* __restrict__ b3,
           float* __restrict__ out) {
    __shared__ __attribute__((aligned(16))) unsigned short xs[2][ROWS][XC]; // 107520 B
    __shared__ __attribute__((aligned(16))) unsigned short h1[ROWS][136];   // 8704 B
    __shared__ __attribute__((aligned(16))) unsigned short h2[ROWS][136];   // 8704 B

    const int tid  = threadIdx.x;
    const int lane = tid & 63;
    const int wv   = tid >> 6;            // 0..7
    const bool is_copy = (wv >= 4);
    const int l15  = lane & 15;
    const int lk   = lane >> 4;           // 0..3
    const int wv_m = (wv >> 1) & 1;       // compute: row half
    const int wv_n = wv & 1;              // compute: frag half
    const int wr   = wv_m * 16;
    const int nb   = wv_n * 4;            // frags nb..min(nb+3,6)
    const size_t b0 = (size_t)blockIdx.x * (TILES * ROWS);

    const unsigned short* weff = wst;
    const unsigned short* w2t  = wst + W2T_OFF;
    const unsigned short* w3t  = wst + W3T_OFF;

    // ---- prologue: zero xs col-pads (784..831, both bufs) and h k-pads
    for (int i = tid; i < 1536; i += NT) {
        const int buf = i / 768, r = (i % 768) / 24, c = (i % 768) % 24;
        *reinterpret_cast<unsigned int*>(&xs[buf][r][784 + c * 2]) = 0u;
    }
    for (int i = tid; i < 1152; i += NT) {
        const int a = i / 576, r = (i % 576) / 18, c = (i % 576) % 18;
        unsigned short* hp = a ? &h2[0][0] : &h1[0][0];
        *reinterpret_cast<unsigned int*>(hp + r * 136 + 100 + c * 2) = 0u;
    }
    // ---- prologue: all 512 threads copy tile 0 (flat, coalesced)
    {
        const float* src = x + b0 * 784;
#pragma unroll
        for (int i = 0; i < 13; ++i) {
            const int f = i * 2048 + tid * 4;
            if (f < ROWS * 784) {
                const float4 v = *reinterpret_cast<const float4*>(src + f);
                const int row = f / 784, col = f - row * 784;
                *reinterpret_cast<uint2*>(&xs[0][row][col]) =
                    (uint2){pkbf(v.x, v.y), pkbf(v.z, v.w)};
            }
        }
    }
    __syncthreads();

    // compute-wave constants
    float bias1[4], bias2[4], bb3 = 0.f;
    const unsigned short* bp[4];
    if (!is_copy) {
#pragma unroll
        for (int j = 0; j < 4; ++j) {
            const int nf = nb + j, c = nf * 16 + l15;
            bias1[j] = (nf < 7 && c < 100) ? b1[c] : 0.f;
            bias2[j] = (nf < 7 && c < 100) ? b2[c] : 0.f;
            bp[j] = weff + (size_t)(nf * 16 + l15) * KP1;   // addr only; deref guarded
        }
        if (wv_n == 0 && l15 < 10) bb3 = b3[l15];
    }

    // copy half-tile: iters [i0,i1), 256 copy lanes, flat coalesced
    auto copy_half = [&](int t1, int i0, int i1) {
        const int ctid = tid - 256;
        const float* src = x + (b0 + (size_t)t1 * ROWS) * 784;
        unsigned short* dst = &xs[t1 & 1][0][0];
#pragma unroll
        for (int i = i0; i < i1; ++i) {
            const int f = i * 1024 + ctid * 4;
            if (f < ROWS * 784) {
                const float4 v = *reinterpret_cast<const float4*>(src + f);
                const int row = f / 784, col = f - row * 784;
                *reinterpret_cast<uint2*>(dst + row * XC + col) =
                    (uint2){pkbf(v.x, v.y), pkbf(v.z, v.w)};
            }
        }
    };

#pragma unroll 1
    for (int t = 0; t < TILES; ++t) {
        const unsigned short* xb = &xs[t & 1][0][0];

        // ======== phase A: copy first half of t+1  |  GEMM1(t) + h1
        if (is_copy) {
            if (t + 1 < TILES) copy_half(t + 1, 0, 13);
        } else {
            f32x4 acc[4];
#pragma unroll
            for (int j = 0; j < 4; ++j) acc[j] = (f32x4){0.f, 0.f, 0.f, 0.f};

            bf16x8 A[2][2];          // [buf][ks]
            bf16x8 Bv[2][4][2];      // [buf][frag][ks]
            const unsigned short* ap = xb + (wr + l15) * XC;

            auto loadW = [&](int w, int b) {
                A[b][0] = *reinterpret_cast<const bf16x8*>(ap + w * 64 + lk * 8);
                A[b][1] = *reinterpret_cast<const bf16x8*>(ap + w * 64 + 32 + lk * 8);
#pragma unroll
                for (int j = 0; j < 4; ++j)
                    if (nb + j < 7) {
                        Bv[b][j][0] = *reinterpret_cast<const bf16x8*>(bp[j] + w * 64 + lk * 8);
                        Bv[b][j][1] = *reinterpret_cast<const bf16x8*>(bp[j] + w * 64 + 32 + lk * 8);
                    }
            };
            loadW(0, 0);
#pragma unroll
            for (int w = 0; w < 13; ++w) {
                if (w < 12) loadW(w + 1, (w + 1) & 1);
                SBAR0;
#pragma unroll
                for (int ks = 0; ks < 2; ++ks)
#pragma unroll
                    for (int j = 0; j < 4; ++j)
                        if (nb + j < 7)
                            acc[j] = __builtin_amdgcn_mfma_f32_16x16x32_bf16(
                                A[w & 1][ks], Bv[w & 1][j][ks], acc[j], 0, 0, 0);
                SBAR0;
            }
            // h1 = relu(acc + b1)
#pragma unroll
            for (int j = 0; j < 4; ++j) {
                const int nf = nb + j, col = nf * 16 + l15;
                if (nf < 7 && col < 100)
#pragma unroll
                    for (int q = 0; q < 4; ++q)
                        h1[wr + lk * 4 + q][col] = f2bf(fmaxf(acc[j][q] + bias1[j], 0.f));
            }
        }
        __syncthreads();

        // ======== phase B: copy second half of t+1  |  GEMM2 + h2
        if (is_copy) {
            if (t + 1 < TILES) copy_half(t + 1, 13, 25);
        } else {
            f32x4 acc2[4];
#pragma unroll
            for (int j = 0; j < 4; ++j) acc2[j] = (f32x4){0.f, 0.f, 0.f, 0.f};
#pragma unroll
            for (int ks = 0; ks < 4; ++ks) {
                const int kb = ks * 32 + lk * 8;
                const bf16x8 af = *reinterpret_cast<const bf16x8*>(&h1[wr + l15][kb]);
#pragma unroll
                for (int j = 0; j < 4; ++j) {
                    const int nf = nb + j;
                    if (nf < 7) {
                        const bf16x8 bfr = *reinterpret_cast<const bf16x8*>(
                            w2t + (size_t)(nf * 16 + l15) * K2P + kb);
                        acc2[j] = __builtin_amdgcn_mfma_f32_16x16x32_bf16(af, bfr, acc2[j], 0, 0, 0);
                    }
                }
            }
#pragma unroll
            for (int j = 0; j < 4; ++j) {
                const int nf = nb + j, col = nf * 16 + l15;
                if (nf < 7 && col < 100)
#pragma unroll
                    for (int q = 0; q < 4; ++q)
                        h2[wr + lk * 4 + q][col] = f2bf(fmaxf(acc2[j][q] + bias2[j], 0.f));
            }
        }
        __syncthreads();

        // ======== phase C (no barrier): GEMM3 + store by wv_n==0 computers
        if (!is_copy && wv_n == 0) {
            f32x4 acc3 = (f32x4){0.f, 0.f, 0.f, 0.f};
#pragma unroll
            for (int ks = 0; ks < 4; ++ks) {
                const int kb = ks * 32 + lk * 8;
                const bf16x8 bfr = *reinterpret_cast<const bf16x8*>(
                    w3t + (size_t)l15 * K2P + kb);
                const bf16x8 af = *reinterpret_cast<const bf16x8*>(&h2[wr + l15][kb]);
                acc3 = __builtin_amdgcn_mfma_f32_16x16x32_bf16(af, bfr, acc3, 0, 0, 0);
            }
            if (l15 < 10) {
#pragma unroll
                for (int q = 0; q < 4; ++q) {
                    const size_t row = b0 + (size_t)t * ROWS + wr + lk * 4 + q;
                    out[row * 10 + l15] = acc3[q] + bb3;
                }
            }
        }
    }
}

extern "C" void kernel_launch(void* const* d_in, const int* in_sizes, int n_in,
                              void* d_out, int out_size, void* d_ws, size_t ws_size,
                              hipStream_t stream) {
    const float* x      = (const float*)d_in[0];
    const float* w_conv = (const float*)d_in[1];
    const float* W1     = (const float*)d_in[2];
    const float* b1     = (const float*)d_in[3];
    const float* W2     = (const float*)d_in[4];
    const float* b2     = (const float*)d_in[5];
    const float* W3     = (const float*)d_in[6];
    const float* b3     = (const float*)d_in[7];
    float* out = (float*)d_out;
    unsigned short* ws = (unsigned short*)d_ws;

    const int total = 28 * KP1 + NP * K2P + 16 * K2P;   // 39680
    build_weights<<<(total + 255) / 256, 256, 0, stream>>>(w_conv, W1, W2, W3, ws);
    fused<<<32768 / (TILES * ROWS), NT, 0, stream>>>(x, ws, b1, b2, b3, out);
}